// Round 13
// baseline (110.907 us; speedup 1.0000x reference)
//
#include <hip/hip_runtime.h>
#include <hip/hip_fp16.h>

#define BB 8
#define NN 200000
#define HH 480
#define WW 640
#define HWSZ (HH * WW)
#define BH 4                        // rows per slice
#define NSL (HH / BH)               // 120 slices
#define STRIDE 2048                 // u64 slots per (b,slice); mean ~1667, +9sd
#define AE ((size_t)BB * NSL * STRIDE)   // arena u64 elements per tref
#define NBKT (2 * BB * NSL)         // 1920 (t,b,s) buckets
#define ROWPIX 1280                 // 2 pol x 640 cells per boundary row

#define EPB2 1024
#define BPB2 ((NN + EPB2 - 1) / EPB2)    // 196

// LDS accumulator: 6 rows (top halo r0-1, 4 real, bottom halo) x 2 pol x
// 642 cols x 2 column-shifted copies of u32 {w:16 lo, wt:16 hi}, scale 512.
#define ROWW   1284                 // u32 words per row (2 pol x 642)
#define CPYW   (6 * ROWW)           // 7704 words per copy
#define ACCW   (2 * CPYW)           // 15408 words = 61.6 KB

// ---------------------------------------------------------------------------
// K0: flow interleave + Charbonnier smoothness; block 0 zeroes counters.
// ---------------------------------------------------------------------------
__global__ void __launch_bounds__(256) flow_prep(
        const float* __restrict__ flow, __half2* __restrict__ fxy,
        unsigned int* __restrict__ counters, float* __restrict__ out) {
    if (blockIdx.x == 0)
        for (int i = threadIdx.x; i < NBKT; i += 256) counters[i] = 0;
    const int total = BB * HWSZ;
    float s = 0.0f;
    for (int i = blockIdx.x * 256 + threadIdx.x; i < total;
         i += gridDim.x * 256) {
        int b = i / HWSZ, pix = i % HWSZ;
        const float* fb = flow + (size_t)b * 2 * HWSZ;
        float f0 = fb[pix], f1 = fb[HWSZ + pix];
        fxy[i] = __floats2half2_rn(f0, f1);
        int w = pix % WW, h = pix / WW;
        if (h < HH - 1) {
            float d0 = f0 - fb[pix + WW];
            float d1 = f1 - fb[HWSZ + pix + WW];
            s += sqrtf(d0 * d0 + 1e-6f) + sqrtf(d1 * d1 + 1e-6f);
        }
        if (w < WW - 1) {
            float d0 = f0 - fb[pix + 1];
            float d1 = f1 - fb[HWSZ + pix + 1];
            s += sqrtf(d0 * d0 + 1e-6f) + sqrtf(d1 * d1 + 1e-6f);
        }
    }
    #pragma unroll
    for (int off = 32; off > 0; off >>= 1)
        s += __shfl_down(s, off, 64);
    __shared__ float ls[4];
    int lane = threadIdx.x & 63, wid = threadIdx.x >> 6;
    if (lane == 0) ls[wid] = s;
    __syncthreads();
    if (threadIdx.x == 0)
        atomicAdd(out, ls[0] + ls[1] + ls[2] + ls[3]);
}

// ---------------------------------------------------------------------------
// K1: warp each event for BOTH trefs; DUAL-FREE bucket = floor(wy)>>2
// (f=-1 -> bucket 0). 240-counter hist + scan + in-block counting sort,
// coalesced arena writes. payload (R7-proven): [qy:20@38][qx:21@17]
// [pol:1@16][qt:16@0], coords (v+2)*2048.
// ---------------------------------------------------------------------------
__global__ void __launch_bounds__(256) warp_place(
        const float4* __restrict__ ev, const __half2* __restrict__ fxy,
        unsigned int* __restrict__ counters,
        unsigned long long* __restrict__ arena) {
    __shared__ unsigned int h[2 * NSL];
    __shared__ unsigned int lbase[2 * NSL];
    __shared__ unsigned int gbase[2 * NSL];
    __shared__ unsigned int wsum[4];
    __shared__ unsigned int grand;
    __shared__ unsigned long long staged[2 * EPB2];      // 2048 x 8B = 16 KB
    __shared__ unsigned char sid[2 * EPB2];
    int b     = blockIdx.x & 7;            // XCD-affinity: batch b -> XCD b
    int chunk = blockIdx.x >> 3;
    int tid   = threadIdx.x;
    if (tid < 2 * NSL) h[tid] = 0;
    __syncthreads();

    const float4*  evb = ev  + (size_t)b * NN;
    const __half2* fb  = fxy + (size_t)b * HWSZ;
    int base = chunk * EPB2;

    unsigned long long pay[2][4];
    unsigned short code[2][4];             // 0 invalid; else c+1
    #pragma unroll
    for (int k = 0; k < 4; ++k) {
        code[0][k] = 0; code[1][k] = 0;
        int e = base + k * 256 + tid;
        if (e < NN) {
            float4 E = evb[e];
            int gpix = (int)(E.y * 640.0f + E.z);
            float2 f = __half22float2(fb[gpix]);
            unsigned int pol = (E.w < 0.0f) ? 1u : 0u;
            #pragma unroll
            for (int t = 0; t < 2; ++t) {
                float tref = (t == 0) ? 1.0f : 0.0f;
                float dt = tref - E.x;
                float wy = fmaf(dt * f.y, 640.0f, E.y);   // flow_scaling=640
                float wx = fmaf(dt * f.x, 640.0f, E.z);
                if (wx >= -1.0f && wx < 640.0f && wy >= -1.0f && wy < 480.0f) {
                    int fr = (int)floorf(wy);             // -1..479
                    int s0 = (fr < 0) ? 0 : (fr >> 2);
                    int c = t * NSL + s0;
                    code[t][k] = (unsigned short)(c + 1);
                    float tw = (t == 0) ? E.x : (1.0f - E.x);
                    unsigned int qy = (unsigned int)((wy + 2.0f) * 2048.0f);
                    unsigned int qx = (unsigned int)((wx + 2.0f) * 2048.0f);
                    unsigned int qt = (unsigned int)fmaf(tw, 65535.0f, 0.5f);
                    pay[t][k] = ((unsigned long long)qy << 38)
                              | ((unsigned long long)qx << 17)
                              | ((unsigned long long)pol << 16)
                              | (unsigned long long)qt;
                    atomicAdd(&h[c], 1u);
                }
            }
        }
    }
    __syncthreads();

    // exclusive scan of 240 counters; reserve global ranges
    {
        int lane = tid & 63, wid = tid >> 6;
        unsigned int val = (tid < 2 * NSL) ? h[tid] : 0u;
        unsigned int inc = val;
        #pragma unroll
        for (int off = 1; off < 64; off <<= 1) {
            unsigned int tv = __shfl_up(inc, off, 64);
            if (lane >= off) inc += tv;
        }
        if (lane == 63) wsum[wid] = inc;
        __syncthreads();
        if (tid == 0) {
            unsigned int a = 0;
            #pragma unroll
            for (int k = 0; k < 4; ++k) { unsigned int tmp = wsum[k]; wsum[k] = a; a += tmp; }
        }
        __syncthreads();
        if (tid < 2 * NSL) {
            unsigned int lb = wsum[wid] + inc - val;
            lbase[tid] = lb;
            if (tid == 2 * NSL - 1) grand = lb + val;
            int t = tid / NSL, s = tid % NSL;
            gbase[tid] = h[tid] ? atomicAdd(&counters[(t * BB + b) * NSL + s], h[tid]) : 0u;
            h[tid] = 0;                    // reuse as cursor
        }
    }
    __syncthreads();

    // counting sort into LDS staging
    #pragma unroll
    for (int t = 0; t < 2; ++t) {
        #pragma unroll
        for (int k = 0; k < 4; ++k) {
            unsigned int cd = code[t][k];
            if (cd) {
                int c = (int)cd - 1;
                unsigned int pos = lbase[c] + atomicAdd(&h[c], 1u);
                staged[pos] = pay[t][k];
                sid[pos] = (unsigned char)c;
            }
        }
    }
    __syncthreads();

    // coalesced copy to arena
    unsigned int G = grand;
    for (unsigned int p = tid; p < G; p += 256) {
        int c = (int)sid[p];
        int t = (c >= NSL) ? 1 : 0;
        int s = c - t * NSL;
        unsigned int off = gbase[c] + (p - lbase[c]);
        if (off < STRIDE)
            arena[(size_t)t * AE + ((size_t)(b * NSL + s)) * STRIDE + off] = staged[p];
    }
}

// ---------------------------------------------------------------------------
// K2 phase A: one block (1024 thr) per (b,slice); both trefs serial.
// Pair-u64 LDS atomics (UNCHANGED decode/accumulate). Reduce rows 2..4
// (complete in-block); write row 1 (first-real partial) and row 5 (bottom
// halo) packed u32 to global for phase B. Row 0 discarded (OOB).
// ---------------------------------------------------------------------------
__global__ void __launch_bounds__(1024) slice_accum(
        const unsigned long long* __restrict__ arena,
        const unsigned int* __restrict__ counters,
        unsigned int* __restrict__ part, unsigned int* __restrict__ halo,
        float* __restrict__ out) {
    __shared__ unsigned int accw[ACCW];    // 61.6 KB
    __shared__ float ls[16];
    const int b = blockIdx.x & 7;          // XCD-affinity
    const int s = blockIdx.x >> 3;
    const int tid = threadIdx.x;
    const int r0 = s * BH;

    #pragma unroll
    for (int t = 0; t < 2; ++t) {
        uint4* az = (uint4*)accw;
        for (int i = tid; i < ACCW / 4; i += 1024)
            az[i] = make_uint4(0u, 0u, 0u, 0u);
        __syncthreads();

        unsigned int cnt = counters[(t * BB + b) * NSL + s];
        if (cnt > STRIDE) cnt = STRIDE;
        const ulonglong2* cell2 = (const ulonglong2*)(
            arena + (size_t)t * AE + (size_t)(b * NSL + s) * STRIDE);
        unsigned int n2 = (cnt + 1u) >> 1;
        for (unsigned int i2 = tid; i2 < n2; i2 += 1024) {
            ulonglong2 v = cell2[i2];
            #pragma unroll
            for (int j = 0; j < 2; ++j) {
                unsigned long long q = j ? v.y : v.x;
                if (2u * i2 + (unsigned int)j >= cnt) continue;
                unsigned int lo = (unsigned int)q, hi = (unsigned int)(q >> 32);
                int qt  = (int)(lo & 0xFFFFu);
                int pol = (int)((lo >> 16) & 1u);
                unsigned int qx = ((lo >> 17) | (hi << 15)) & 0x1FFFFFu;
                unsigned int qy = (hi >> 6) & 0xFFFFFu;
                int cc = (int)(qx >> 11) - 1;            // left col +1: 0..640
                int rr = (int)(qy >> 11) - 1 - r0;       // LDS row: 0..4
                int rxi = (int)(qx & 2047u), ryi = (int)(qy & 2047u);
                int irx = 2048 - rxi, iry = 2048 - ryi;
                int w00 = (__mul24(iry, irx) + 4096) >> 13;  // scale 512
                int w01 = (__mul24(iry, rxi) + 4096) >> 13;
                int w10 = (__mul24(ryi, irx) + 4096) >> 13;
                int w11 = (__mul24(ryi, rxi) + 4096) >> 13;
                int t00 = (__mul24(w00, qt) + 32768) >> 16;
                int t01 = (__mul24(w01, qt) + 32768) >> 16;
                int t10 = (__mul24(w10, qt) + 32768) >> 16;
                int t11 = (__mul24(w11, qt) + 32768) >> 16;
                unsigned long long v0 =
                    ((unsigned long long)(unsigned int)(w01 | (t01 << 16)) << 32)
                    | (unsigned int)(w00 | (t00 << 16));
                unsigned long long v1 =
                    ((unsigned long long)(unsigned int)(w11 | (t11 << 16)) << 32)
                    | (unsigned int)(w10 | (t10 << 16));
                int sel = cc & 1;
                int idx = cc + sel + (sel ? CPYW : 0);   // copy B if odd start
                int a0  = rr * ROWW + pol * 642 + idx;
                unsigned long long* p0 = (unsigned long long*)&accw[a0];
                atomicAdd(p0, v0);                       // row rr
                atomicAdd(p0 + (ROWW / 2), v1);          // row rr+1
            }
        }
        __syncthreads();

        // rows 2..4 reduced here; row 1 -> part, row 5 -> halo, row 0 dropped
        float sum = 0.0f;
        const int bkt = (t * BB + b) * NSL + s;
        for (int wi = tid; wi < CPYW; wi += 1024) {
            int row = wi / ROWW;
            if (row == 0) continue;
            int colw = wi - row * ROWW;
            int pol = (colw >= 642) ? 1 : 0;
            int ci = colw - pol * 642;
            if (ci == 0 || ci == 641) continue;          // halo cols
            unsigned int a  = accw[wi];
            unsigned int bb = accw[wi + 1 + CPYW];       // copy B partner
            unsigned int w  = (a & 0xFFFFu) + (bb & 0xFFFFu);
            unsigned int wt = (a >> 16) + (bb >> 16);
            if (row >= 2 && row <= 4) {
                if (w) {
                    float r = (float)wt * __builtin_amdgcn_rcpf((float)w);
                    sum += r * r;
                }
            } else {
                unsigned int packed = w | (wt << 16);
                unsigned int gi = (unsigned int)bkt * ROWPIX + pol * WW + (ci - 1);
                if (row == 1) part[gi] = packed;
                else          halo[gi] = packed;         // row 5
            }
        }
        #pragma unroll
        for (int off = 32; off > 0; off >>= 1)
            sum += __shfl_down(sum, off, 64);
        int lane = tid & 63, wid = tid >> 6;
        if (lane == 0) ls[wid] = sum;
        __syncthreads();
        if (tid == 0) {
            float tot = 0.0f;
            #pragma unroll
            for (int k = 0; k < 16; ++k) tot += ls[k];
            atomicAdd(out, tot);
        }
        __syncthreads();
    }
}

// ---------------------------------------------------------------------------
// K3 phase B: boundary rows. cell = part[bkt] + (s>0 ? halo[bkt-1] : 0).
// ---------------------------------------------------------------------------
__global__ void __launch_bounds__(256) boundary_reduce(
        const unsigned int* __restrict__ part,
        const unsigned int* __restrict__ halo, float* __restrict__ out) {
    const unsigned int total = (unsigned int)NBKT * ROWPIX;   // 2.458M
    float sum = 0.0f;
    for (unsigned int j = blockIdx.x * 256 + threadIdx.x; j < total;
         j += gridDim.x * 256) {
        unsigned int bkt = j / ROWPIX;
        unsigned int s = bkt % NSL;
        unsigned int p = part[j];
        unsigned int hh = (s > 0) ? halo[j - ROWPIX] : 0u;
        unsigned int w  = (p & 0xFFFFu) + (hh & 0xFFFFu);
        if (!w) continue;
        unsigned int wt = (p >> 16) + (hh >> 16);
        float r = (float)wt * __builtin_amdgcn_rcpf((float)w);
        sum += r * r;
    }
    #pragma unroll
    for (int off = 32; off > 0; off >>= 1)
        sum += __shfl_down(sum, off, 64);
    __shared__ float ls[4];
    int lane = threadIdx.x & 63, wid = threadIdx.x >> 6;
    if (lane == 0) ls[wid] = sum;
    __syncthreads();
    if (threadIdx.x == 0)
        atomicAdd(out, ls[0] + ls[1] + ls[2] + ls[3]);
}

extern "C" void kernel_launch(void* const* d_in, const int* in_sizes, int n_in,
                              void* d_out, int out_size, void* d_ws, size_t ws_size,
                              hipStream_t stream) {
    const float*  flow = (const float*)d_in[0];   // [B,2,H,W]
    const float4* ev   = (const float4*)d_in[1];  // [B,N,4]
    float* out = (float*)d_out;

    // ws: arena u64[2*AE] 31.5MB | fxy 9.83MB | counters 7.7KB
    //   | part u32[NBKT*1280] 9.83MB | halo 9.83MB  -> ~61 MB
    unsigned long long* arena = (unsigned long long*)d_ws;
    char* p = (char*)d_ws + 2 * AE * sizeof(unsigned long long);
    __half2* fxy = (__half2*)p;            p += (size_t)BB * HWSZ * sizeof(__half2);
    unsigned int* counters = (unsigned int*)p; p += (size_t)NBKT * sizeof(unsigned int);
    unsigned int* part = (unsigned int*)p; p += (size_t)NBKT * ROWPIX * sizeof(unsigned int);
    unsigned int* halo = (unsigned int*)p;

    hipMemsetAsync(out, 0, sizeof(float), stream);

    flow_prep<<<1024, 256, 0, stream>>>(flow, fxy, counters, out);
    warp_place<<<8 * BPB2, 256, 0, stream>>>(ev, fxy, counters, arena);
    slice_accum<<<8 * NSL, 1024, 0, stream>>>(arena, counters, part, halo, out);
    boundary_reduce<<<960, 256, 0, stream>>>(part, halo, out);
}

// Round 14
// 89.527 us; speedup vs baseline: 1.2388x; 1.2388x over previous
//
#include <hip/hip_runtime.h>

#define BB 8
#define NN 200000
#define HH 480
#define WW 640
#define HWSZ (HH * WW)
#define BH 4                        // rows per slice
#define NSL (HH / BH)               // 120 slices
#define STRIDE 3584                 // u64 slots per (b,slice); mean ~2050
#define AE ((size_t)BB * NSL * STRIDE)   // arena u64 elements per tref

#define EPB2 1024
#define BPB2 ((NN + EPB2 - 1) / EPB2)    // 196

// LDS accumulator: 6 rows (halo 0,5) x 2 pol x 642 cols x 2 col-shifted
// copies of u32 {w:16 lo, wt:16 hi}, scale 512.
#define ROWW   1284                 // u32 words per row (2 pol x 642)
#define CPYW   (6 * ROWW)           // 7704 words per copy
#define ACCW   (2 * CPYW)           // 15408 words = 61.6 KB

// ---------------------------------------------------------------------------
// K1 (R11-proven + direct flow gather): warp both trefs; 240-counter hist;
// in-block counting sort; coalesced arena writes. payload:
// [qy:20@38][qx:21@17][pol:1@16][qt:16@0], coords (v+2)*2048.
// Straddlers replicated into both buckets (absolute coords).
// ---------------------------------------------------------------------------
__global__ void __launch_bounds__(256) warp_place_dual(
        const float4* __restrict__ ev, const float* __restrict__ flow,
        unsigned int* __restrict__ counters,
        unsigned long long* __restrict__ arena) {
    __shared__ unsigned int h[2 * NSL];        // counts -> cursor
    __shared__ unsigned int lbase[2 * NSL];
    __shared__ unsigned int gbase[2 * NSL];
    __shared__ unsigned int wsum[4];
    __shared__ unsigned int grand;
    __shared__ unsigned long long staged[2 * EPB2 * 2];  // 4096 x 8B = 32 KB
    __shared__ unsigned char sid[2 * EPB2 * 2];
    int b     = blockIdx.x & 7;            // XCD-affinity: batch b -> XCD b
    int chunk = blockIdx.x >> 3;
    int tid   = threadIdx.x;
    if (tid < 2 * NSL) h[tid] = 0;
    __syncthreads();

    const float4* evb = ev   + (size_t)b * NN;
    const float*  fb  = flow + (size_t)b * 2 * HWSZ;   // L2-resident (2.46MB)
    int base = chunk * EPB2;

    unsigned long long pay[2][4];
    unsigned short code[2][4];             // 0 invalid; else (c+1) | dual<<10
    #pragma unroll
    for (int k = 0; k < 4; ++k) {
        code[0][k] = 0; code[1][k] = 0;
        int e = base + k * 256 + tid;
        if (e < NN) {
            float4 E = evb[e];
            int gpix = (int)(E.y * 640.0f + E.z);
            float fx = fb[gpix];
            float fy = fb[HWSZ + gpix];
            unsigned int pol = (E.w < 0.0f) ? 1u : 0u;
            #pragma unroll
            for (int t = 0; t < 2; ++t) {
                float tref = (t == 0) ? 1.0f : 0.0f;
                float dt = tref - E.x;
                float wy = fmaf(dt * fy, 640.0f, E.y);   // flow_scaling=640
                float wx = fmaf(dt * fx, 640.0f, E.z);
                if (wx >= -1.0f && wx < 640.0f && wy >= -2.0f && wy < 481.0f) {
                    int ity = (int)floorf(wy);
                    int r1 = ity + 1;
                    bool v0 = (ity >= 0) && (ity < HH);
                    bool v1 = (r1  >= 0) && (r1  < HH);
                    int s0 = -1; bool dual = false;
                    if (v0) { s0 = ity >> 2; dual = v1 && ((r1 >> 2) != s0); }
                    else if (v1) s0 = r1 >> 2;
                    if (s0 >= 0) {
                        int c = t * NSL + s0;
                        code[t][k] = (unsigned short)((c + 1) | (dual ? 0x400 : 0));
                        float tw = (t == 0) ? E.x : (1.0f - E.x);
                        unsigned int qy = (unsigned int)((wy + 2.0f) * 2048.0f);
                        unsigned int qx = (unsigned int)((wx + 2.0f) * 2048.0f);
                        unsigned int qt = (unsigned int)fmaf(tw, 65535.0f, 0.5f);
                        pay[t][k] = ((unsigned long long)qy << 38)
                                  | ((unsigned long long)qx << 17)
                                  | ((unsigned long long)pol << 16)
                                  | (unsigned long long)qt;
                        atomicAdd(&h[c], 1u);
                        if (dual) atomicAdd(&h[c + 1], 1u);
                    }
                }
            }
        }
    }
    __syncthreads();

    // exclusive scan of 240 counters; reserve global ranges
    {
        int lane = tid & 63, wid = tid >> 6;
        unsigned int val = (tid < 2 * NSL) ? h[tid] : 0u;
        unsigned int inc = val;
        #pragma unroll
        for (int off = 1; off < 64; off <<= 1) {
            unsigned int tv = __shfl_up(inc, off, 64);
            if (lane >= off) inc += tv;
        }
        if (lane == 63) wsum[wid] = inc;
        __syncthreads();
        if (tid == 0) {
            unsigned int a = 0;
            #pragma unroll
            for (int k = 0; k < 4; ++k) { unsigned int tmp = wsum[k]; wsum[k] = a; a += tmp; }
        }
        __syncthreads();
        if (tid < 2 * NSL) {
            unsigned int lb = wsum[wid] + inc - val;
            lbase[tid] = lb;
            if (tid == 2 * NSL - 1) grand = lb + val;
            int t = tid / NSL, s = tid % NSL;
            gbase[tid] = h[tid] ? atomicAdd(&counters[(t * BB + b) * NSL + s], h[tid]) : 0u;
            h[tid] = 0;                    // reuse as cursor
        }
    }
    __syncthreads();

    // counting sort into LDS staging
    #pragma unroll
    for (int t = 0; t < 2; ++t) {
        #pragma unroll
        for (int k = 0; k < 4; ++k) {
            unsigned int cd = code[t][k];
            if (cd) {
                int c = (int)(cd & 0x3ff) - 1;
                unsigned int pos = lbase[c] + atomicAdd(&h[c], 1u);
                staged[pos] = pay[t][k];
                sid[pos] = (unsigned char)c;
                if (cd & 0x400) {
                    pos = lbase[c + 1] + atomicAdd(&h[c + 1], 1u);
                    staged[pos] = pay[t][k];
                    sid[pos] = (unsigned char)(c + 1);
                }
            }
        }
    }
    __syncthreads();

    // coalesced copy to arena
    unsigned int G = grand;
    for (unsigned int p = tid; p < G; p += 256) {
        int c = (int)sid[p];
        int t = (c >= NSL) ? 1 : 0;
        int s = c - t * NSL;
        unsigned int off = gbase[c] + (p - lbase[c]);
        if (off < STRIDE)
            arena[(size_t)t * AE + ((size_t)(b * NSL + s)) * STRIDE + off] = staged[p];
    }
}

// ---------------------------------------------------------------------------
// K2 (R11-proven + fused smoothness): one block (1024 thr) per (b,slice);
// both trefs serial. Pair-u64 LDS atomics; reduce rows 1..4 (full values,
// straddlers replicated); halo rows 0,5 discarded. Then the block computes
// its rows' Charbonnier smoothness terms (hidden, flow stripe is 25.6 KB).
// ---------------------------------------------------------------------------
__global__ void __launch_bounds__(1024) slice_accum_fused(
        const unsigned long long* __restrict__ arena,
        const unsigned int* __restrict__ counters,
        const float* __restrict__ flow, float* __restrict__ out) {
    __shared__ unsigned int accw[ACCW];    // 61.6 KB
    __shared__ float ls[16];
    const int b = blockIdx.x & 7;          // XCD-affinity
    const int s = blockIdx.x >> 3;
    const int tid = threadIdx.x;
    const int r0 = s * BH;

    #pragma unroll
    for (int t = 0; t < 2; ++t) {
        uint4* az = (uint4*)accw;
        for (int i = tid; i < ACCW / 4; i += 1024)
            az[i] = make_uint4(0u, 0u, 0u, 0u);
        __syncthreads();

        unsigned int cnt = counters[(t * BB + b) * NSL + s];
        if (cnt > STRIDE) cnt = STRIDE;
        const ulonglong2* cell2 = (const ulonglong2*)(
            arena + (size_t)t * AE + (size_t)(b * NSL + s) * STRIDE);
        unsigned int n2 = (cnt + 1u) >> 1;
        for (unsigned int i2 = tid; i2 < n2; i2 += 1024) {
            ulonglong2 v = cell2[i2];
            #pragma unroll
            for (int j = 0; j < 2; ++j) {
                unsigned long long q = j ? v.y : v.x;
                if (2u * i2 + (unsigned int)j >= cnt) continue;
                unsigned int lo = (unsigned int)q, hi = (unsigned int)(q >> 32);
                int qt  = (int)(lo & 0xFFFFu);
                int pol = (int)((lo >> 16) & 1u);
                unsigned int qx = ((lo >> 17) | (hi << 15)) & 0x1FFFFFu;
                unsigned int qy = (hi >> 6) & 0xFFFFFu;
                int cc = (int)(qx >> 11) - 1;            // left col +1: 0..640
                int rr = (int)(qy >> 11) - 1 - r0;       // LDS row: 0..4
                int rxi = (int)(qx & 2047u), ryi = (int)(qy & 2047u);
                int irx = 2048 - rxi, iry = 2048 - ryi;
                int w00 = (__mul24(iry, irx) + 4096) >> 13;  // scale 512
                int w01 = (__mul24(iry, rxi) + 4096) >> 13;
                int w10 = (__mul24(ryi, irx) + 4096) >> 13;
                int w11 = (__mul24(ryi, rxi) + 4096) >> 13;
                int t00 = (__mul24(w00, qt) + 32768) >> 16;
                int t01 = (__mul24(w01, qt) + 32768) >> 16;
                int t10 = (__mul24(w10, qt) + 32768) >> 16;
                int t11 = (__mul24(w11, qt) + 32768) >> 16;
                unsigned long long v0 =
                    ((unsigned long long)(unsigned int)(w01 | (t01 << 16)) << 32)
                    | (unsigned int)(w00 | (t00 << 16));
                unsigned long long v1 =
                    ((unsigned long long)(unsigned int)(w11 | (t11 << 16)) << 32)
                    | (unsigned int)(w10 | (t10 << 16));
                int sel = cc & 1;
                int idx = cc + sel + (sel ? CPYW : 0);   // copy B if odd start
                int a0  = rr * ROWW + pol * 642 + idx;
                unsigned long long* p0 = (unsigned long long*)&accw[a0];
                atomicAdd(p0, v0);                       // row rr
                atomicAdd(p0 + (ROWW / 2), v1);          // row rr+1
            }
        }
        __syncthreads();

        // fused ratio reduce over real cells (rows 1..4, cols 1..640)
        float sum = 0.0f;
        for (int wi = tid; wi < CPYW; wi += 1024) {
            int row = wi / ROWW;
            if (row == 0 || row == 5) continue;          // halo rows
            int colw = wi - row * ROWW;
            int ci = (colw >= 642) ? colw - 642 : colw;
            if (ci == 0 || ci == 641) continue;          // halo cols
            unsigned int a  = accw[wi];
            unsigned int bb = accw[wi + 1 + CPYW];       // copy B partner
            unsigned int w  = (a & 0xFFFFu) + (bb & 0xFFFFu);
            if (!w) continue;
            unsigned int wt = (a >> 16) + (bb >> 16);
            float r = (float)wt * __builtin_amdgcn_rcpf((float)w);
            sum += r * r;
        }
        #pragma unroll
        for (int off = 32; off > 0; off >>= 1)
            sum += __shfl_down(sum, off, 64);
        int lane = tid & 63, wid = tid >> 6;
        if (lane == 0) ls[wid] = sum;
        __syncthreads();
        if (tid == 0) {
            float tot = 0.0f;
            #pragma unroll
            for (int k = 0; k < 16; ++k) tot += ls[k];
            atomicAdd(out, tot);
        }
        __syncthreads();                   // protect accw/ls reuse
    }

    // --- fused Charbonnier smoothness for this block's rows r0..r0+3 ---
    float sm = 0.0f;
    for (int i = tid; i < BH * WW * 2; i += 1024) {
        int ch = i / (BH * WW);
        int rem = i - ch * (BH * WW);
        int rh = rem / WW, w = rem - rh * WW;
        int hrow = r0 + rh;
        const float* p = flow + ((size_t)b * 2 + ch) * HWSZ + hrow * WW + w;
        float v = p[0];
        if (hrow < HH - 1) {
            float d = v - p[WW];
            sm += sqrtf(d * d + 1e-6f);
        }
        if (w < WW - 1) {
            float d = v - p[1];
            sm += sqrtf(d * d + 1e-6f);
        }
    }
    #pragma unroll
    for (int off = 32; off > 0; off >>= 1)
        sm += __shfl_down(sm, off, 64);
    int lane = tid & 63, wid = tid >> 6;
    if (lane == 0) ls[wid] = sm;
    __syncthreads();
    if (tid == 0) {
        float tot = 0.0f;
        #pragma unroll
        for (int k = 0; k < 16; ++k) tot += ls[k];
        atomicAdd(out, tot);
    }
}

extern "C" void kernel_launch(void* const* d_in, const int* in_sizes, int n_in,
                              void* d_out, int out_size, void* d_ws, size_t ws_size,
                              hipStream_t stream) {
    const float*  flow = (const float*)d_in[0];   // [B,2,H,W]
    const float4* ev   = (const float4*)d_in[1];  // [B,N,4]
    float* out = (float*)d_out;

    // ws: arena u64[2*AE] (55.1 MB) | counters u32[2*BB*NSL]
    unsigned long long* arena = (unsigned long long*)d_ws;
    unsigned int* counters = (unsigned int*)((char*)d_ws +
                              2 * AE * sizeof(unsigned long long));

    hipMemsetAsync(out, 0, sizeof(float), stream);
    hipMemsetAsync(counters, 0, 2 * BB * NSL * sizeof(unsigned int), stream);

    warp_place_dual<<<8 * BPB2, 256, 0, stream>>>(ev, flow, counters, arena);
    slice_accum_fused<<<8 * NSL, 1024, 0, stream>>>(arena, counters, flow, out);
}

// Round 15
// 88.155 us; speedup vs baseline: 1.2581x; 1.0156x over previous
//
#include <hip/hip_runtime.h>
#include <hip/hip_fp16.h>

#define BB 8
#define NN 200000
#define HH 480
#define WW 640
#define HWSZ (HH * WW)
#define BH 4                        // rows per slice
#define NSL (HH / BH)               // 120 slices
#define STRIDE 3584                 // u64 slots per (b,slice); mean ~2050
#define AE ((size_t)BB * NSL * STRIDE)   // arena u64 elements per tref

#define EPB2 768
#define BPB2 ((NN + EPB2 - 1) / EPB2)    // 261
#define SCAP (EPB2 * 4)                  // 3072: hard worst-case staging

// LDS accumulator: 6 rows (halo 0,5) x 2 pol x 642 cols x 2 col-shifted
// copies of u32 {w:16 lo, wt:16 hi}, scale 512.
#define ROWW   1284                 // u32 words per row (2 pol x 642)
#define CPYW   (6 * ROWW)           // 7704 words per copy
#define ACCW   (2 * CPYW)           // 15408 words = 61.6 KB

// ---------------------------------------------------------------------------
// K0: flow -> interleaved half2 fxy (2.46 MB/batch, XCD-L2-resident gather
// target); block 0 zeroes bucket counters. Smoothness stays fused in K2.
// ---------------------------------------------------------------------------
__global__ void __launch_bounds__(256) fxy_prep(
        const float* __restrict__ flow, __half2* __restrict__ fxy,
        unsigned int* __restrict__ counters) {
    if (blockIdx.x == 0)
        for (int i = threadIdx.x; i < 2 * BB * NSL; i += 256) counters[i] = 0;
    const int total = BB * HWSZ;
    for (int i = blockIdx.x * 256 + threadIdx.x; i < total;
         i += gridDim.x * 256) {
        int b = i / HWSZ, pix = i - b * HWSZ;
        const float* fb = flow + (size_t)b * 2 * HWSZ;
        fxy[i] = __floats2half2_rn(fb[pix], fb[HWSZ + pix]);
    }
}

// ---------------------------------------------------------------------------
// K1: warp both trefs; 240-counter hist; in-block counting sort (no sid --
// bits 58=t / 59=dualcopy ride in the payload; accum's field masks ignore
// them); coalesced arena writes. payload: [qy:20@38][qx:21@17][pol:1@16]
// [qt:16@0], coords (v+2)*2048. ~27 KB LDS -> 5 blocks/CU.
// ---------------------------------------------------------------------------
__global__ void __launch_bounds__(256) warp_place_dual(
        const float4* __restrict__ ev, const __half2* __restrict__ fxy,
        unsigned int* __restrict__ counters,
        unsigned long long* __restrict__ arena) {
    __shared__ unsigned int h[2 * NSL];        // counts -> cursor
    __shared__ unsigned int lbase[2 * NSL];
    __shared__ unsigned int gbase[2 * NSL];
    __shared__ unsigned int wsum[4];
    __shared__ unsigned int grand;
    __shared__ unsigned long long staged[SCAP];  // 3072 x 8B = 24 KB
    int b     = blockIdx.x & 7;            // XCD-affinity: batch b -> XCD b
    int chunk = blockIdx.x >> 3;
    int tid   = threadIdx.x;
    if (tid < 2 * NSL) h[tid] = 0;
    __syncthreads();

    const float4*  evb = ev  + (size_t)b * NN;
    const __half2* fb  = fxy + (size_t)b * HWSZ;
    int base = chunk * EPB2;

    unsigned long long pay[2][3];
    unsigned short code[2][3];             // 0 invalid; else (c+1) | dual<<10
    #pragma unroll
    for (int k = 0; k < 3; ++k) {
        code[0][k] = 0; code[1][k] = 0;
        int e = base + k * 256 + tid;
        if (e < NN) {
            float4 E = evb[e];
            int gpix = (int)(E.y * 640.0f + E.z);
            float2 f = __half22float2(fb[gpix]);    // (fx, fy)
            unsigned int pol = (E.w < 0.0f) ? 1u : 0u;
            #pragma unroll
            for (int t = 0; t < 2; ++t) {
                float tref = (t == 0) ? 1.0f : 0.0f;
                float dt = tref - E.x;
                float wy = fmaf(dt * f.y, 640.0f, E.y);   // flow_scaling=640
                float wx = fmaf(dt * f.x, 640.0f, E.z);
                if (wx >= -1.0f && wx < 640.0f && wy >= -2.0f && wy < 481.0f) {
                    int ity = (int)floorf(wy);
                    int r1 = ity + 1;
                    bool v0 = (ity >= 0) && (ity < HH);
                    bool v1 = (r1  >= 0) && (r1  < HH);
                    int s0 = -1; bool dual = false;
                    if (v0) { s0 = ity >> 2; dual = v1 && ((r1 >> 2) != s0); }
                    else if (v1) s0 = r1 >> 2;
                    if (s0 >= 0) {
                        int c = t * NSL + s0;
                        code[t][k] = (unsigned short)((c + 1) | (dual ? 0x400 : 0));
                        float tw = (t == 0) ? E.x : (1.0f - E.x);
                        unsigned int qy = (unsigned int)((wy + 2.0f) * 2048.0f);
                        unsigned int qx = (unsigned int)((wx + 2.0f) * 2048.0f);
                        unsigned int qt = (unsigned int)fmaf(tw, 65535.0f, 0.5f);
                        pay[t][k] = ((unsigned long long)qy << 38)
                                  | ((unsigned long long)qx << 17)
                                  | ((unsigned long long)pol << 16)
                                  | (unsigned long long)qt
                                  | ((unsigned long long)t << 58);
                        atomicAdd(&h[c], 1u);
                        if (dual) atomicAdd(&h[c + 1], 1u);
                    }
                }
            }
        }
    }
    __syncthreads();

    // exclusive scan of 240 counters; reserve global ranges
    {
        int lane = tid & 63, wid = tid >> 6;
        unsigned int val = (tid < 2 * NSL) ? h[tid] : 0u;
        unsigned int inc = val;
        #pragma unroll
        for (int off = 1; off < 64; off <<= 1) {
            unsigned int tv = __shfl_up(inc, off, 64);
            if (lane >= off) inc += tv;
        }
        if (lane == 63) wsum[wid] = inc;
        __syncthreads();
        if (tid == 0) {
            unsigned int a = 0;
            #pragma unroll
            for (int k = 0; k < 4; ++k) { unsigned int tmp = wsum[k]; wsum[k] = a; a += tmp; }
        }
        __syncthreads();
        if (tid < 2 * NSL) {
            unsigned int lb = wsum[wid] + inc - val;
            lbase[tid] = lb;
            if (tid == 2 * NSL - 1) grand = lb + val;
            int t = tid / NSL, s = tid % NSL;
            gbase[tid] = h[tid] ? atomicAdd(&counters[(t * BB + b) * NSL + s], h[tid]) : 0u;
            h[tid] = 0;                    // reuse as cursor
        }
    }
    __syncthreads();

    // counting sort into LDS staging (dual copies get bit 59)
    #pragma unroll
    for (int t = 0; t < 2; ++t) {
        #pragma unroll
        for (int k = 0; k < 3; ++k) {
            unsigned int cd = code[t][k];
            if (cd) {
                int c = (int)(cd & 0x3ff) - 1;
                unsigned int pos = lbase[c] + atomicAdd(&h[c], 1u);
                staged[pos] = pay[t][k];
                if (cd & 0x400) {
                    pos = lbase[c + 1] + atomicAdd(&h[c + 1], 1u);
                    staged[pos] = pay[t][k] | (1ull << 59);
                }
            }
        }
    }
    __syncthreads();

    // coalesced copy to arena; bucket decoded from payload bits
    unsigned int G = grand;
    for (unsigned int p = tid; p < G; p += 256) {
        unsigned long long q = staged[p];
        int t    = (int)((q >> 58) & 1u);
        int dual = (int)((q >> 59) & 1u);
        unsigned int qy = (unsigned int)(q >> 38) & 0xFFFFFu;
        int ity = (int)(qy >> 11) - 2;
        int s0 = ((ity < 0) ? 0 : (ity >> 2)) + dual;
        int c = t * NSL + s0;
        unsigned int off = gbase[c] + (p - lbase[c]);
        if (off < STRIDE)
            arena[(size_t)t * AE + ((size_t)(b * NSL + s0)) * STRIDE + off] = q;
    }
}

// ---------------------------------------------------------------------------
// K2 (UNCHANGED from R14): one block (1024 thr) per (b,slice); both trefs
// serial. Pair-u64 LDS atomics; reduce rows 1..4; fused Charbonnier
// smoothness for this block's rows.
// ---------------------------------------------------------------------------
__global__ void __launch_bounds__(1024) slice_accum_fused(
        const unsigned long long* __restrict__ arena,
        const unsigned int* __restrict__ counters,
        const float* __restrict__ flow, float* __restrict__ out) {
    __shared__ unsigned int accw[ACCW];    // 61.6 KB
    __shared__ float ls[16];
    const int b = blockIdx.x & 7;          // XCD-affinity
    const int s = blockIdx.x >> 3;
    const int tid = threadIdx.x;
    const int r0 = s * BH;

    #pragma unroll
    for (int t = 0; t < 2; ++t) {
        uint4* az = (uint4*)accw;
        for (int i = tid; i < ACCW / 4; i += 1024)
            az[i] = make_uint4(0u, 0u, 0u, 0u);
        __syncthreads();

        unsigned int cnt = counters[(t * BB + b) * NSL + s];
        if (cnt > STRIDE) cnt = STRIDE;
        const ulonglong2* cell2 = (const ulonglong2*)(
            arena + (size_t)t * AE + (size_t)(b * NSL + s) * STRIDE);
        unsigned int n2 = (cnt + 1u) >> 1;
        for (unsigned int i2 = tid; i2 < n2; i2 += 1024) {
            ulonglong2 v = cell2[i2];
            #pragma unroll
            for (int j = 0; j < 2; ++j) {
                unsigned long long q = j ? v.y : v.x;
                if (2u * i2 + (unsigned int)j >= cnt) continue;
                unsigned int lo = (unsigned int)q, hi = (unsigned int)(q >> 32);
                int qt  = (int)(lo & 0xFFFFu);
                int pol = (int)((lo >> 16) & 1u);
                unsigned int qx = ((lo >> 17) | (hi << 15)) & 0x1FFFFFu;
                unsigned int qy = (hi >> 6) & 0xFFFFFu;
                int cc = (int)(qx >> 11) - 1;            // left col +1: 0..640
                int rr = (int)(qy >> 11) - 1 - r0;       // LDS row: 0..4
                int rxi = (int)(qx & 2047u), ryi = (int)(qy & 2047u);
                int irx = 2048 - rxi, iry = 2048 - ryi;
                int w00 = (__mul24(iry, irx) + 4096) >> 13;  // scale 512
                int w01 = (__mul24(iry, rxi) + 4096) >> 13;
                int w10 = (__mul24(ryi, irx) + 4096) >> 13;
                int w11 = (__mul24(ryi, rxi) + 4096) >> 13;
                int t00 = (__mul24(w00, qt) + 32768) >> 16;
                int t01 = (__mul24(w01, qt) + 32768) >> 16;
                int t10 = (__mul24(w10, qt) + 32768) >> 16;
                int t11 = (__mul24(w11, qt) + 32768) >> 16;
                unsigned long long v0 =
                    ((unsigned long long)(unsigned int)(w01 | (t01 << 16)) << 32)
                    | (unsigned int)(w00 | (t00 << 16));
                unsigned long long v1 =
                    ((unsigned long long)(unsigned int)(w11 | (t11 << 16)) << 32)
                    | (unsigned int)(w10 | (t10 << 16));
                int sel = cc & 1;
                int idx = cc + sel + (sel ? CPYW : 0);   // copy B if odd start
                int a0  = rr * ROWW + pol * 642 + idx;
                unsigned long long* p0 = (unsigned long long*)&accw[a0];
                atomicAdd(p0, v0);                       // row rr
                atomicAdd(p0 + (ROWW / 2), v1);          // row rr+1
            }
        }
        __syncthreads();

        // fused ratio reduce over real cells (rows 1..4, cols 1..640)
        float sum = 0.0f;
        for (int wi = tid; wi < CPYW; wi += 1024) {
            int row = wi / ROWW;
            if (row == 0 || row == 5) continue;          // halo rows
            int colw = wi - row * ROWW;
            int ci = (colw >= 642) ? colw - 642 : colw;
            if (ci == 0 || ci == 641) continue;          // halo cols
            unsigned int a  = accw[wi];
            unsigned int bb = accw[wi + 1 + CPYW];       // copy B partner
            unsigned int w  = (a & 0xFFFFu) + (bb & 0xFFFFu);
            if (!w) continue;
            unsigned int wt = (a >> 16) + (bb >> 16);
            float r = (float)wt * __builtin_amdgcn_rcpf((float)w);
            sum += r * r;
        }
        #pragma unroll
        for (int off = 32; off > 0; off >>= 1)
            sum += __shfl_down(sum, off, 64);
        int lane = tid & 63, wid = tid >> 6;
        if (lane == 0) ls[wid] = sum;
        __syncthreads();
        if (tid == 0) {
            float tot = 0.0f;
            #pragma unroll
            for (int k = 0; k < 16; ++k) tot += ls[k];
            atomicAdd(out, tot);
        }
        __syncthreads();                   // protect accw/ls reuse
    }

    // --- fused Charbonnier smoothness for this block's rows r0..r0+3 ---
    float sm = 0.0f;
    for (int i = tid; i < BH * WW * 2; i += 1024) {
        int ch = i / (BH * WW);
        int rem = i - ch * (BH * WW);
        int rh = rem / WW, w = rem - rh * WW;
        int hrow = r0 + rh;
        const float* p = flow + ((size_t)b * 2 + ch) * HWSZ + hrow * WW + w;
        float v = p[0];
        if (hrow < HH - 1) {
            float d = v - p[WW];
            sm += sqrtf(d * d + 1e-6f);
        }
        if (w < WW - 1) {
            float d = v - p[1];
            sm += sqrtf(d * d + 1e-6f);
        }
    }
    #pragma unroll
    for (int off = 32; off > 0; off >>= 1)
        sm += __shfl_down(sm, off, 64);
    int lane = tid & 63, wid = tid >> 6;
    if (lane == 0) ls[wid] = sm;
    __syncthreads();
    if (tid == 0) {
        float tot = 0.0f;
        #pragma unroll
        for (int k = 0; k < 16; ++k) tot += ls[k];
        atomicAdd(out, tot);
    }
}

extern "C" void kernel_launch(void* const* d_in, const int* in_sizes, int n_in,
                              void* d_out, int out_size, void* d_ws, size_t ws_size,
                              hipStream_t stream) {
    const float*  flow = (const float*)d_in[0];   // [B,2,H,W]
    const float4* ev   = (const float4*)d_in[1];  // [B,N,4]
    float* out = (float*)d_out;

    // ws: arena u64[2*AE] (55.1 MB) | fxy half2[B*HW] (9.83 MB) | counters
    unsigned long long* arena = (unsigned long long*)d_ws;
    __half2* fxy = (__half2*)((char*)d_ws + 2 * AE * sizeof(unsigned long long));
    unsigned int* counters = (unsigned int*)((char*)fxy +
                              (size_t)BB * HWSZ * sizeof(__half2));

    hipMemsetAsync(out, 0, sizeof(float), stream);

    fxy_prep<<<2048, 256, 0, stream>>>(flow, fxy, counters);
    warp_place_dual<<<8 * BPB2, 256, 0, stream>>>(ev, fxy, counters, arena);
    slice_accum_fused<<<8 * NSL, 1024, 0, stream>>>(arena, counters, flow, out);
}